// Round 6
// baseline (737.771 us; speedup 1.0000x reference)
//
#include <hip/hip_runtime.h>
#include <float.h>

// Pipeline (all replica-f32 semantics confirmed passing in round 5):
//   conv1/2/3: f32 sequential fused-FMA (ic,kh,kw), bias at end, relu  [exact]
//   rownorm:   sx/sc pairwise-8                                        [exact]
//   split:     x,c -> bf16 hi/lo pairs (for MFMA screen)
//   screen:    MFMA bf16x3 GEMM approximating q=fl(fl(sx+sc)-2*dot), per-row
//              top-2 (m1,i1,m2) per 128-code block; |q_scr - q_ref| <= ~1e-7
//   fix:       merge 64 blocks; if gap >= TAU=1e-6 winner is provably the
//              replica argmin; else exact replica recompute over all 8192
//              codes with first-index ties (np.argmin semantics)
//
// Workspace (float slots, ~54.6 MB) — out1 region is reused by VQ buffers
// after conv2 has consumed it (stream-ordered):
//   out1  : ws[0 .. 8388608)        [16][32][128][128]
//     pm1 = ws+0        [64][16384] f32   (aliased, written post-conv2)
//     pi1 = ws+1048576  [64][16384] i32
//     pm2 = ws+2097152  [64][16384] f32
//     xh  = ws+3145728  (ushort[1048576])
//     xl  = ws+3670016  (ushort[1048576])
//     ch  = ws+4194304  (ushort[524288])
//     cl  = ws+4456448  (ushort[524288])
//   out2  : ws+8388608   [16][64][64][64]
//   flat  : ws+12582912  [16384][64]
//   sx    : ws+13631488  [16384]
//   sc    : ws+13647872  [8192]

#define TAU 1e-6f

typedef __attribute__((ext_vector_type(8))) short s16x8;
typedef __attribute__((ext_vector_type(4))) float f32x4;

static __device__ __forceinline__ unsigned short f2bf(float f) {
    unsigned u = __float_as_uint(f);
    u = (u + 0x7fffu + ((u >> 16) & 1u)) >> 16;    // RN-even; no NaN in this data
    return (unsigned short)u;
}
static __device__ __forceinline__ float bf2f(unsigned short h) {
    return __uint_as_float(((unsigned)h) << 16);
}

// ---------------- conv1: x[16,3,256,256] -> relu -> out1[16,32,128,128], k4 s2 p1
__global__ __launch_bounds__(256) void conv1_kernel(const float* __restrict__ in,
                                                    const float* __restrict__ w,   // [32][3][4][4]
                                                    const float* __restrict__ bias,// [32]
                                                    float* __restrict__ out) {
    int p = blockIdx.x * 256 + threadIdx.x;        // 262144
    int ow = p & 127, oh = (p >> 7) & 127, bb = p >> 14;
    float taps[48];                                 // [ic][kh][kw]
    for (int ic = 0; ic < 3; ++ic) {
        const float* ip = in + (bb * 3 + ic) * 65536;
        #pragma unroll
        for (int kh = 0; kh < 4; ++kh) {
            int ih = oh * 2 - 1 + kh;
            #pragma unroll
            for (int kw = 0; kw < 4; ++kw) {
                int iw = ow * 2 - 1 + kw;
                bool ok = ((unsigned)ih < 256u) && ((unsigned)iw < 256u);
                taps[ic * 16 + kh * 4 + kw] = ok ? ip[ih * 256 + iw] : 0.0f;
            }
        }
    }
    float* op = out + bb * (32 * 16384) + oh * 128 + ow;
    for (int oc = 0; oc < 32; ++oc) {
        float acc = 0.0f;
        const float* wp = w + oc * 48;             // wave-uniform
        #pragma unroll
        for (int t = 0; t < 48; ++t) acc = __fmaf_rn(taps[t], wp[t], acc);
        acc = __fadd_rn(acc, bias[oc]);
        op[oc * 16384] = fmaxf(acc, 0.0f);
    }
}

// ---------------- conv2: out1 -> relu -> out2[16,64,64,64]  ((ic,kh,kw) chain)
__global__ __launch_bounds__(256) void conv2_kernel(const float* __restrict__ in,
                                                    const float* __restrict__ w,   // [64][32][4][4]
                                                    const float* __restrict__ bias,
                                                    float* __restrict__ out) {
    int p = blockIdx.x * 256 + threadIdx.x;        // 65536
    int ow = p & 63, oh = (p >> 6) & 63, bb = p >> 12;
    int oc0 = blockIdx.y * 16;
    float acc[16];
    #pragma unroll
    for (int j = 0; j < 16; ++j) acc[j] = 0.0f;
    const float* ibase = in + bb * 32 * 16384;
    for (int ic = 0; ic < 32; ++ic) {
        const float* ip = ibase + ic * 16384;
        float taps[16];
        #pragma unroll
        for (int kh = 0; kh < 4; ++kh) {
            int ih = oh * 2 - 1 + kh;
            #pragma unroll
            for (int kw = 0; kw < 4; ++kw) {
                int iw = ow * 2 - 1 + kw;
                bool ok = ((unsigned)ih < 128u) && ((unsigned)iw < 128u);
                taps[kh * 4 + kw] = ok ? ip[ih * 128 + iw] : 0.0f;
            }
        }
        #pragma unroll
        for (int t = 0; t < 16; ++t) {
            float tp = taps[t];
            #pragma unroll
            for (int j = 0; j < 16; ++j)
                acc[j] = __fmaf_rn(tp, w[(oc0 + j) * 512 + ic * 16 + t], acc[j]);
        }
    }
    float* op = out + bb * (64 * 4096) + oh * 64 + ow;
    #pragma unroll
    for (int j = 0; j < 16; ++j) {
        float y = __fadd_rn(acc[j], bias[oc0 + j]);
        op[(oc0 + j) * 4096] = fmaxf(y, 0.0f);
    }
}

// ---------------- conv3: out2 -> relu -> flat[16384][64]  ((ic,kh,kw) chain)
__global__ __launch_bounds__(256) void conv3_kernel(const float* __restrict__ in,
                                                    const float* __restrict__ w,   // [64][64][4][4]
                                                    const float* __restrict__ bias,
                                                    float* __restrict__ flat) {
    int p = blockIdx.x * 256 + threadIdx.x;        // 16384 (== flat row)
    int ow = p & 31, oh = (p >> 5) & 31, bb = p >> 10;
    int oc0 = blockIdx.y * 8;
    float acc[8];
    #pragma unroll
    for (int j = 0; j < 8; ++j) acc[j] = 0.0f;
    const float* ibase = in + bb * 64 * 4096;
    for (int ic = 0; ic < 64; ++ic) {
        const float* ip = ibase + ic * 4096;
        float taps[16];
        #pragma unroll
        for (int kh = 0; kh < 4; ++kh) {
            int ih = oh * 2 - 1 + kh;
            #pragma unroll
            for (int kw = 0; kw < 4; ++kw) {
                int iw = ow * 2 - 1 + kw;
                bool ok = ((unsigned)ih < 64u) && ((unsigned)iw < 64u);
                taps[kh * 4 + kw] = ok ? ip[ih * 64 + iw] : 0.0f;
            }
        }
        #pragma unroll
        for (int t = 0; t < 16; ++t) {
            float tp = taps[t];
            #pragma unroll
            for (int j = 0; j < 8; ++j)
                acc[j] = __fmaf_rn(tp, w[(oc0 + j) * 1024 + ic * 16 + t], acc[j]);
        }
    }
    float* op = flat + (size_t)p * 64 + oc0;
    #pragma unroll
    for (int j = 0; j < 8; ++j) {
        float y = __fadd_rn(acc[j], bias[oc0 + j]);
        op[j] = fmaxf(y, 0.0f);
    }
}

// ---------------- row norms: sx[16384], sc[8192] (pairwise-8, as in round 5)
__global__ __launch_bounds__(256) void rownorm_kernel(const float* __restrict__ flat,
                                                      const float* __restrict__ cb,
                                                      float* __restrict__ sx,
                                                      float* __restrict__ sc) {
    int i = blockIdx.x * 256 + threadIdx.x;        // 24576
    const float* src;
    float* dst;
    if (i < 16384) { src = flat + (size_t)i * 64; dst = sx + i; }
    else           { src = cb + (size_t)(i - 16384) * 64; dst = sc + (i - 16384); }
    float r[8];
    #pragma unroll
    for (int j = 0; j < 8; ++j) r[j] = __fmul_rn(src[j], src[j]);
    #pragma unroll
    for (int b = 1; b < 8; ++b)
        #pragma unroll
        for (int j = 0; j < 8; ++j)
            r[j] = __fadd_rn(r[j], __fmul_rn(src[b * 8 + j], src[b * 8 + j]));
    float s01 = __fadd_rn(r[0], r[1]), s23 = __fadd_rn(r[2], r[3]);
    float s45 = __fadd_rn(r[4], r[5]), s67 = __fadd_rn(r[6], r[7]);
    *dst = __fadd_rn(__fadd_rn(s01, s23), __fadd_rn(s45, s67));
}

// ---------------- split: f32 -> bf16 hi/lo for flat and codebook
__global__ __launch_bounds__(256) void split_kernel(const float* __restrict__ flat,
                                                    const float* __restrict__ cb,
                                                    unsigned short* __restrict__ xh,
                                                    unsigned short* __restrict__ xl,
                                                    unsigned short* __restrict__ ch,
                                                    unsigned short* __restrict__ cl) {
    int i = blockIdx.x * 256 + threadIdx.x;        // 1048576 + 524288 = 1572864
    float v;
    unsigned short *ph, *pl;
    if (i < 1048576) { v = flat[i]; ph = xh + i; pl = xl + i; }
    else             { int j = i - 1048576; v = cb[j]; ph = ch + j; pl = cl + j; }
    unsigned short h = f2bf(v);
    unsigned short l = f2bf(v - bf2f(h));
    *ph = h; *pl = l;
}

// ---------------- MFMA screen: per-row top-2 of approx q over 128-code blocks
// grid (128 Mblk, 64 Nblk), 256 thr (4 waves, 2x2 of 64x64)
__global__ __launch_bounds__(256) void vq_screen_kernel(const unsigned short* __restrict__ xh,
                                                        const unsigned short* __restrict__ xl,
                                                        const unsigned short* __restrict__ ch,
                                                        const unsigned short* __restrict__ cl,
                                                        const float* __restrict__ sx,
                                                        const float* __restrict__ sc,
                                                        float* __restrict__ pm1,   // [64][16384]
                                                        int* __restrict__ pi1,
                                                        float* __restrict__ pm2) {
    __shared__ float sxs[128], scs[128];
    __shared__ float rm1[2][128];
    __shared__ int ri1[2][128];
    __shared__ float rm2[2][128];
    int tid = threadIdx.x;
    int mb = blockIdx.x, nb = blockIdx.y;
    int row0 = mb * 128, col0 = nb * 128;
    if (tid < 128) sxs[tid] = sx[row0 + tid];
    else scs[tid - 128] = sc[col0 + tid - 128];
    __syncthreads();

    int w = tid >> 6, lane = tid & 63;
    int wr = w >> 1, wc = w & 1;
    int le = lane & 15, lk = lane >> 4;            // entity idx, k-chunk

    // A fragments: rows mbase+ifrag*16+le, 16B at k = koff + lk*8
    s16x8 a[4][4];                                  // [ifrag][xh-k0, xh-k1, xl-k0, xl-k1]
    #pragma unroll
    for (int i = 0; i < 4; ++i) {
        size_t arow = (size_t)(row0 + wr * 64 + i * 16 + le) * 64 + lk * 8;
        a[i][0] = *(const s16x8*)(xh + arow);
        a[i][1] = *(const s16x8*)(xh + arow + 32);
        a[i][2] = *(const s16x8*)(xl + arow);
        a[i][3] = *(const s16x8*)(xl + arow + 32);
    }

    f32x4 acc[4][4];
    #pragma unroll
    for (int i = 0; i < 4; ++i)
        #pragma unroll
        for (int j = 0; j < 4; ++j) acc[i][j] = (f32x4){0.f, 0.f, 0.f, 0.f};

    // segments: xh*ch(k0,k1), xh*cl(k0,k1), xl*ch(k0,k1)
    const unsigned short* bsrc[6] = {ch, ch, cl, cl, ch, ch};
    const int bko[6] = {0, 32, 0, 32, 0, 32};
    const int aid[6] = {0, 1, 0, 1, 2, 3};
    #pragma unroll
    for (int s = 0; s < 6; ++s) {
        s16x8 b[4];
        #pragma unroll
        for (int j = 0; j < 4; ++j) {
            size_t brow = (size_t)(col0 + wc * 64 + j * 16 + le) * 64 + bko[s] + lk * 8;
            b[j] = *(const s16x8*)(bsrc[s] + brow);
        }
        #pragma unroll
        for (int i = 0; i < 4; ++i)
            #pragma unroll
            for (int j = 0; j < 4; ++j)
                acc[i][j] = __builtin_amdgcn_mfma_f32_16x16x32_bf16(a[i][aid[s]], b[j], acc[i][j], 0, 0, 0);
    }

    // epilogue: q = fadd(sx,sc) fmaf(-2,dot,.); top-2 per row over wave's 64 cols
    #pragma unroll
    for (int i = 0; i < 4; ++i) {
        #pragma unroll
        for (int reg = 0; reg < 4; ++reg) {
            int rl = wr * 64 + i * 16 + lk * 4 + reg;   // row within block tile
            float sxv = sxs[rl];
            float m1 = FLT_MAX, m2 = FLT_MAX;
            int i1 = 0x7fffffff;
            #pragma unroll
            for (int j = 0; j < 4; ++j) {
                int colL = wc * 64 + j * 16 + le;
                float t1 = __fadd_rn(sxv, scs[colL]);
                float q = __fmaf_rn(-2.0f, acc[i][j][reg], t1);
                int code = col0 + colL;
                if (q < m1) { m2 = m1; m1 = q; i1 = code; }
                else if (q < m2) { m2 = q; }
            }
            // butterfly across the 16 cols (lanes with same lk)
            #pragma unroll
            for (int mask = 1; mask < 16; mask <<= 1) {
                float om1 = __shfl_xor(m1, mask);
                int oi1 = __shfl_xor(i1, mask);
                float om2 = __shfl_xor(m2, mask);
                float nm2 = fminf(fminf(m2, om2), fmaxf(m1, om1));
                int ni1 = (om1 < m1) ? oi1 : ((om1 == m1 && oi1 < i1) ? oi1 : i1);
                float nm1 = fminf(m1, om1);
                m1 = nm1; i1 = ni1; m2 = nm2;
            }
            if (le == 0) { rm1[wc][rl] = m1; ri1[wc][rl] = i1; rm2[wc][rl] = m2; }
        }
    }
    __syncthreads();
    if (tid < 128) {
        float a1 = rm1[0][tid], b1 = rm1[1][tid];
        int ai = ri1[0][tid], bi = ri1[1][tid];
        float a2 = rm2[0][tid], b2 = rm2[1][tid];
        float m1 = fminf(a1, b1);
        int i1 = (b1 < a1) ? bi : ((b1 == a1 && bi < ai) ? bi : ai);
        float m2 = fminf(fminf(a2, b2), fmaxf(a1, b1));
        size_t o = (size_t)nb * 16384 + row0 + tid;
        pm1[o] = m1; pi1[o] = i1; pm2[o] = m2;
    }
}

// ---------------- fix: merge 64 N-blocks; exact replica repair if gap < TAU
__global__ __launch_bounds__(64) void vq_fix_kernel(const float* __restrict__ flat,
                                                    const float* __restrict__ cb,
                                                    const float* __restrict__ sx,
                                                    const float* __restrict__ sc,
                                                    const float* __restrict__ pm1,
                                                    const int* __restrict__ pi1,
                                                    const float* __restrict__ pm2,
                                                    float* __restrict__ out) {
    __shared__ float xv[64];
    int r = blockIdx.x;                            // 16384 rows
    int t = threadIdx.x;                           // one wave

    if (r == 0 && t == 0) out[16384] = 0.0f;       // tuple second output

    size_t o = (size_t)t * 16384 + r;
    float m1 = pm1[o], m2 = pm2[o];
    int i1 = pi1[o];
    #pragma unroll
    for (int mask = 1; mask < 64; mask <<= 1) {
        float om1 = __shfl_xor(m1, mask);
        int oi1 = __shfl_xor(i1, mask);
        float om2 = __shfl_xor(m2, mask);
        float nm2 = fminf(fminf(m2, om2), fmaxf(m1, om1));
        int ni1 = (om1 < m1) ? oi1 : ((om1 == m1 && oi1 < i1) ? oi1 : i1);
        float nm1 = fminf(m1, om1);
        m1 = nm1; i1 = ni1; m2 = nm2;
    }

    if (m2 - m1 >= TAU) {                          // screen winner provably exact
        if (t == 0) out[r] = (float)i1;
        return;
    }

    // exact replica recompute over all 8192 codes (first-index ties)
    xv[t] = flat[(size_t)r * 64 + t];
    __syncthreads();
    float sxr = sx[r];
    float bv = FLT_MAX; int bk = 0x7fffffff;
    for (int m = 0; m < 128; ++m) {
        int k = t + 64 * m;                        // ascending k per thread
        const float* c = cb + (size_t)k * 64;
        float dot = 0.0f;
        #pragma unroll
        for (int d = 0; d < 64; ++d) dot = __fmaf_rn(xv[d], c[d], dot);
        float t1 = __fadd_rn(sxr, sc[k]);
        float q = __fmaf_rn(-2.0f, dot, t1);
        if (q < bv) { bv = q; bk = k; }
    }
    #pragma unroll
    for (int mask = 1; mask < 64; mask <<= 1) {
        float ov = __shfl_xor(bv, mask);
        int ok = __shfl_xor(bk, mask);
        if (ov < bv || (ov == bv && ok < bk)) { bv = ov; bk = ok; }
    }
    if (t == 0) out[r] = (float)bk;
}

extern "C" void kernel_launch(void* const* d_in, const int* in_sizes, int n_in,
                              void* d_out, int out_size, void* d_ws, size_t ws_size,
                              hipStream_t stream) {
    const float* x  = (const float*)d_in[0];
    const float* w1 = (const float*)d_in[1];
    const float* b1 = (const float*)d_in[2];
    const float* w2 = (const float*)d_in[3];
    const float* b2 = (const float*)d_in[4];
    const float* w3 = (const float*)d_in[5];
    const float* b3 = (const float*)d_in[6];
    const float* cb = (const float*)d_in[7];

    float* ws   = (float*)d_ws;
    float* out1 = ws;                               // [0, 8388608)
    float* pm1  = ws;                               // aliases into out1 (post-conv2)
    int*   pi1  = (int*)(ws + 1048576);
    float* pm2  = ws + 2097152;
    unsigned short* xh = (unsigned short*)(ws + 3145728);
    unsigned short* xl = (unsigned short*)(ws + 3670016);
    unsigned short* ch = (unsigned short*)(ws + 4194304);
    unsigned short* cl = (unsigned short*)(ws + 4456448);
    float* out2 = ws + 8388608;
    float* flat = ws + 12582912;
    float* sx   = ws + 13631488;
    float* sc   = ws + 13647872;
    float* out  = (float*)d_out;

    hipLaunchKernelGGL(conv1_kernel,  dim3(1024), dim3(256), 0, stream, x, w1, b1, out1);
    hipLaunchKernelGGL(conv2_kernel,  dim3(256, 4), dim3(256), 0, stream, out1, w2, b2, out2);
    hipLaunchKernelGGL(conv3_kernel,  dim3(64, 8), dim3(256), 0, stream, out2, w3, b3, flat);
    hipLaunchKernelGGL(rownorm_kernel, dim3(96), dim3(256), 0, stream, flat, cb, sx, sc);
    hipLaunchKernelGGL(split_kernel,  dim3(6144), dim3(256), 0, stream, flat, cb, xh, xl, ch, cl);
    hipLaunchKernelGGL(vq_screen_kernel, dim3(128, 64), dim3(256), 0, stream,
                       xh, xl, ch, cl, sx, sc, pm1, pi1, pm2);
    hipLaunchKernelGGL(vq_fix_kernel, dim3(16384), dim3(64), 0, stream,
                       flat, cb, sx, sc, pm1, pi1, pm2, out);
}